// Round 2
// baseline (63919.543 us; speedup 1.0000x reference)
//
#include <hip/hip_runtime.h>
#include <math.h>

#define BATCH 512
#define SEQ_T 128
#define NIN   500
#define HID   1024
#define G3    3072   // 3*HID

// ---------------------------------------------------------------------------
// C[M,NN] = A[M,K] @ W[NN,K]^T + bias[NN]
// A row addressing: row r -> A[(r>>9)*a_stride_t + (r&511)*a_stride_b + k]
//   (B=512 is baked in: r = tt*512 + b). For plain 2D A pass a_stride_t=0,
//   a_stride_b=lda (valid while M<=512) or contiguous strides for M>512.
// 64x64 tile, BK=32, 256 threads, 4x4 microtile.
// LDS [k][m] +4 pad: inner A-read is 16-lane broadcast (free), B-read 2-way (free).
// ---------------------------------------------------------------------------
__global__ __launch_bounds__(256) void gemm_nt(
    const float* __restrict__ A, long a_stride_t, long a_stride_b,
    const float* __restrict__ W,
    const float* __restrict__ bias,
    float* __restrict__ C,
    int M, int NN, int K)
{
    __shared__ float As[32][68];
    __shared__ float Bs[32][68];
    const int tid = threadIdx.x;
    const int tx  = tid & 15;
    const int ty  = tid >> 4;
    const int bm  = blockIdx.x * 64;
    const int bn  = blockIdx.y * 64;
    const int lk  = tid & 31;   // k within tile (coalesced global reads)
    const int lr  = tid >> 5;   // row within tile, 8 passes of +8

    // hoist k-invariant row offsets
    long aoff[8], woff[8];
    bool av[8], wv[8];
    #pragma unroll
    for (int i = 0; i < 8; i++) {
        int m  = lr + 8 * i;
        int gm = bm + m;
        int gn = bn + m;
        av[i] = (gm < M);
        wv[i] = (gn < NN);
        aoff[i] = (long)(gm >> 9) * a_stride_t + (long)(gm & 511) * a_stride_b;
        woff[i] = (long)gn * (long)K;
    }

    float acc[4][4] = {};

    for (int k0 = 0; k0 < K; k0 += 32) {
        int  gk = k0 + lk;
        bool kv = (gk < K);
        #pragma unroll
        for (int i = 0; i < 8; i++) {
            int m = lr + 8 * i;
            As[lk][m] = (kv && av[i]) ? A[aoff[i] + gk] : 0.f;
            Bs[lk][m] = (kv && wv[i]) ? W[woff[i] + gk] : 0.f;
        }
        __syncthreads();
        #pragma unroll
        for (int kk = 0; kk < 32; kk++) {
            float4 a4 = *(const float4*)&As[kk][ty * 4];
            float4 b4 = *(const float4*)&Bs[kk][tx * 4];
            float a[4] = {a4.x, a4.y, a4.z, a4.w};
            float b[4] = {b4.x, b4.y, b4.z, b4.w};
            #pragma unroll
            for (int i = 0; i < 4; i++)
                #pragma unroll
                for (int j = 0; j < 4; j++)
                    acc[i][j] = fmaf(a[i], b[j], acc[i][j]);
        }
        __syncthreads();
    }

    #pragma unroll
    for (int i = 0; i < 4; i++) {
        int gm = bm + ty * 4 + i;
        if (gm >= M) continue;
        #pragma unroll
        for (int j = 0; j < 4; j++) {
            int gn = bn + tx * 4 + j;
            if (gn >= NN) continue;
            C[(long)gm * NN + gn] = acc[i][j] + bias[gn];
        }
    }
}

// ---------------------------------------------------------------------------
// GRU elementwise update: r,z from summed projections; n uses r * (h-proj only)
// gx points at this timestep's [B, 3H] slab.
// ---------------------------------------------------------------------------
__global__ __launch_bounds__(256) void gru_update(
    const float* __restrict__ gx,
    const float* __restrict__ gh,
    const float* __restrict__ hprev,
    float* __restrict__ hnew)
{
    int idx = blockIdx.x * 256 + threadIdx.x;
    if (idx >= BATCH * HID) return;
    int b  = idx >> 10;
    int hi = idx & (HID - 1);
    const float* gxr = gx + (long)b * G3;
    const float* ghr = gh + (long)b * G3;
    float xr = gxr[hi], xz = gxr[HID + hi], xn = gxr[2 * HID + hi];
    float hr = ghr[hi], hz = ghr[HID + hi], hn = ghr[2 * HID + hi];
    float r = 1.f / (1.f + expf(-(xr + hr)));
    float z = 1.f / (1.f + expf(-(xz + hz)));
    float n = tanhf(xn + r * hn);
    hnew[idx] = (1.f - z) * n + z * hprev[idx];
}

// ---------------------------------------------------------------------------
// block reductions (256 threads = 4 waves of 64)
// ---------------------------------------------------------------------------
__device__ __forceinline__ float block_reduce_sum(float v) {
    __shared__ float red[4];
    #pragma unroll
    for (int o = 32; o > 0; o >>= 1) v += __shfl_down(v, o);
    __syncthreads();
    if ((threadIdx.x & 63) == 0) red[threadIdx.x >> 6] = v;
    __syncthreads();
    return red[0] + red[1] + red[2] + red[3];
}

__device__ __forceinline__ float block_reduce_max(float v) {
    __shared__ float red[4];
    #pragma unroll
    for (int o = 32; o > 0; o >>= 1) v = fmaxf(v, __shfl_down(v, o));
    __syncthreads();
    if ((threadIdx.x & 63) == 0) red[threadIdx.x >> 6] = v;
    __syncthreads();
    return fmaxf(fmaxf(red[0], red[1]), fmaxf(red[2], red[3]));
}

// ---------------------------------------------------------------------------
// LayerNorm + SiLU, in-place on z [B, H]; one block (256 thr) per row
// ---------------------------------------------------------------------------
__global__ __launch_bounds__(256) void ln_silu(
    float* __restrict__ z,
    const float* __restrict__ gamma,
    const float* __restrict__ beta)
{
    int b = blockIdx.x;
    float* row = z + (long)b * HID;
    float v[4];
    float s = 0.f;
    #pragma unroll
    for (int i = 0; i < 4; i++) { v[i] = row[threadIdx.x + 256 * i]; s += v[i]; }
    float mean = block_reduce_sum(s) * (1.f / HID);
    float vs = 0.f;
    #pragma unroll
    for (int i = 0; i < 4; i++) { float d = v[i] - mean; vs += d * d; }
    float var = block_reduce_sum(vs) * (1.f / HID);
    float inv = 1.f / sqrtf(var + 1e-5f);
    #pragma unroll
    for (int i = 0; i < 4; i++) {
        int col = threadIdx.x + 256 * i;
        float zz = (v[i] - mean) * inv * gamma[col] + beta[col];
        row[col] = zz / (1.f + expf(-zz));   // SiLU
    }
}

// ---------------------------------------------------------------------------
// mask(<0 -> -inf) + softmax + clip[0,0.1] + 20-iter rebalance; block per row
// ---------------------------------------------------------------------------
__global__ __launch_bounds__(256) void head_softmax_rebalance(
    const float* __restrict__ scores,
    float* __restrict__ out)
{
    int b = blockIdx.x;
    const float* srow = scores + (long)b * NIN;
    int i0 = threadIdx.x;
    int i1 = threadIdx.x + 256;
    bool v1 = (i1 < NIN);

    float s0 = srow[i0];
    if (s0 < 0.f) s0 = -INFINITY;
    float s1 = v1 ? srow[i1] : -INFINITY;
    if (s1 < 0.f) s1 = -INFINITY;

    float m  = block_reduce_max(fmaxf(s0, s1));
    float e0 = expf(s0 - m);
    float e1 = v1 ? expf(s1 - m) : 0.f;
    float Z  = block_reduce_sum(e0 + e1);

    float w0 = fminf(fmaxf(e0 / Z, 0.f), 0.1f);
    float w1 = v1 ? fminf(fmaxf(e1 / Z, 0.f), 0.1f) : 0.f;

    for (int it = 0; it < 20; it++) {
        float total  = block_reduce_sum(w0 + w1);
        float excess = total - 1.f;
        bool active  = excess > 1e-6f;
        float sur0 = fmaxf(w0 - 0.1f, 0.f);
        float sur1 = fmaxf(w1 - 0.1f, 0.f);
        float totsur = block_reduce_sum(sur0 + sur1);
        float u0, u1;
        if (totsur > 0.f) {
            float k = excess / fmaxf(totsur, 1e-12f);
            u0 = w0 - sur0 * k;
            u1 = w1 - sur1 * k;
        } else {
            u0 = w0 - excess / (float)NIN;
            u1 = w1 - excess / (float)NIN;
        }
        u0 = fminf(fmaxf(u0, 0.f), 0.1f);
        u1 = fminf(fmaxf(u1, 0.f), 0.1f);
        if (active) { w0 = u0; w1 = u1; }
    }

    out[(long)b * NIN + i0] = w0;
    if (v1) out[(long)b * NIN + i1] = w1;
}

// ---------------------------------------------------------------------------
extern "C" void kernel_launch(void* const* d_in, const int* in_sizes, int n_in,
                              void* d_out, int out_size, void* d_ws, size_t ws_size,
                              hipStream_t stream)
{
    const float* x     = (const float*)d_in[0];
    const float* w_ih0 = (const float*)d_in[1];
    const float* w_hh0 = (const float*)d_in[2];
    const float* b_ih0 = (const float*)d_in[3];
    const float* b_hh0 = (const float*)d_in[4];
    const float* w_ih1 = (const float*)d_in[5];
    const float* w_hh1 = (const float*)d_in[6];
    const float* b_ih1 = (const float*)d_in[7];
    const float* b_hh1 = (const float*)d_in[8];
    const float* w1    = (const float*)d_in[9];
    const float* b1    = (const float*)d_in[10];
    const float* ln_g  = (const float*)d_in[11];
    const float* ln_b  = (const float*)d_in[12];
    const float* w2    = (const float*)d_in[13];
    const float* b2    = (const float*)d_in[14];
    float* out = (float*)d_out;

    // ---- workspace layout ----
    float* ws = (float*)d_ws;
    float* h1a   = ws; ws += (size_t)BATCH * HID;
    float* h1b   = ws; ws += (size_t)BATCH * HID;
    float* hzero = ws; ws += (size_t)BATCH * HID;
    float* gh    = ws; ws += (size_t)BATCH * G3;
    float* zb    = ws; ws += (size_t)BATCH * HID;
    float* sc    = ws; ws += (size_t)BATCH * NIN;
    size_t fixed_floats = (size_t)(ws - (float*)d_ws);

    // choose chunk length Tc by available workspace
    int Tc = 1;
    const int cands[6] = {32, 16, 8, 4, 2, 1};
    for (int ci = 0; ci < 6; ci++) {
        size_t need = fixed_floats + (size_t)cands[ci] * BATCH * (G3 + HID);
        if (need * sizeof(float) <= ws_size) { Tc = cands[ci]; break; }
    }
    float* gxc   = ws; ws += (size_t)Tc * BATCH * G3;  // shared: gx0 then gx1
    float* h0seq = ws;                                  // [Tc][B][H]

    hipMemsetAsync(hzero, 0, (size_t)BATCH * HID * sizeof(float), stream);

    dim3 blk(256);
    dim3 gHH(BATCH / 64, G3 / 64);        // 8 x 48 recurrent gate GEMM
    dim3 gUpd((BATCH * HID) / 256);       // 2048

    const long sBH = (long)BATCH * HID;
    const long sBG = (long)BATCH * G3;

    for (int c = 0; c < SEQ_T / Tc; c++) {
        int t0 = c * Tc;
        // ---- layer-0 x-projection for the whole chunk (one big GEMM) ----
        dim3 gBig((Tc * BATCH) / 64, G3 / 64);
        gemm_nt<<<gBig, blk, 0, stream>>>(x + (long)t0 * NIN, (long)NIN, (long)SEQ_T * NIN,
                                          w_ih0, b_ih0, gxc, Tc * BATCH, G3, NIN);
        // ---- layer-0 recurrence over the chunk ----
        for (int tt = 0; tt < Tc; tt++) {
            const float* prev0 = (tt > 0) ? (h0seq + (long)(tt - 1) * sBH)
                               : (c > 0)  ? (h0seq + (long)(Tc - 1) * sBH)
                                          : hzero;
            gemm_nt<<<gHH, blk, 0, stream>>>(prev0, 0L, (long)HID, w_hh0, b_hh0, gh, BATCH, G3, HID);
            gru_update<<<gUpd, blk, 0, stream>>>(gxc + (long)tt * sBG, gh, prev0, h0seq + (long)tt * sBH);
        }
        // ---- layer-1 x-projection for the chunk (overwrites gxc) ----
        gemm_nt<<<gBig, blk, 0, stream>>>(h0seq, sBH, (long)HID,
                                          w_ih1, b_ih1, gxc, Tc * BATCH, G3, HID);
        // ---- layer-1 recurrence over the chunk ----
        for (int tt = 0; tt < Tc; tt++) {
            int t = t0 + tt;
            float* next1 = (t % 2 == 0) ? h1a : h1b;
            const float* prev1 = (t == 0) ? hzero : ((t % 2 == 0) ? h1b : h1a);
            gemm_nt<<<gHH, blk, 0, stream>>>(prev1, 0L, (long)HID, w_hh1, b_hh1, gh, BATCH, G3, HID);
            gru_update<<<gUpd, blk, 0, stream>>>(gxc + (long)tt * sBG, gh, prev1, next1);
        }
    }
    const float* hT = (SEQ_T % 2 == 0) ? h1b : h1a;   // last write was t=SEQ_T-1 (odd)

    // ---- head ----
    dim3 gZ(BATCH / 64, HID / 64);
    gemm_nt<<<gZ, blk, 0, stream>>>(hT, 0L, (long)HID, w1, b1, zb, BATCH, HID, HID);
    ln_silu<<<dim3(BATCH), blk, 0, stream>>>(zb, ln_g, ln_b);
    dim3 gS(BATCH / 64, (NIN + 63) / 64);
    gemm_nt<<<gS, blk, 0, stream>>>(zb, 0L, (long)HID, w2, b2, sc, BATCH, NIN, HID);
    head_softmax_rebalance<<<dim3(BATCH), blk, 0, stream>>>(sc, out);
}

// Round 3
// 18307.367 us; speedup vs baseline: 3.4915x; 3.4915x over previous
//
#include <hip/hip_runtime.h>
#include <math.h>

#define BATCH 512
#define SEQ_T 128
#define NIN   500
#define HID   1024
#define G3    3072   // 3*HID

typedef short short8 __attribute__((ext_vector_type(8)));
typedef float f32x4  __attribute__((ext_vector_type(4)));

// ---------------------------------------------------------------------------
// fp32 -> 3-way bf16 truncation split: f ~= h + m + l, residual ~2^-24 |f|
// ---------------------------------------------------------------------------
__device__ __forceinline__ void split3(float f, short &h, short &m, short &l) {
    unsigned u = __float_as_uint(f);
    h = (short)(u >> 16);
    float fh = __uint_as_float(u & 0xFFFF0000u);
    float r1 = f - fh;
    unsigned u1 = __float_as_uint(r1);
    m = (short)(u1 >> 16);
    float fm = __uint_as_float(u1 & 0xFFFF0000u);
    float r2 = r1 - fm;
    unsigned u2 = __float_as_uint(r2);
    l = (short)(u2 >> 16);
}

// ---------------------------------------------------------------------------
// C[M,NN] = A[M,K] @ W[NN,K]^T + bias[NN], fp32 in/out, bf16x6 MFMA inside
// (fp32-grade accuracy: products hh+hm+mh+mm+hl+lh, dropped terms <= 2^-26).
// A row addressing: row r -> A[(r>>9)*a_stride_t + (r&511)*a_stride_b + k].
// M must be a multiple of 64 (true for all call sites).
// Block: 256 thr = 4 waves; tile 64x64; each wave a 32x32 quadrant via
// 2x2 v_mfma_f32_16x16x32_bf16. BK=32 (4 k-quads of 8).
// ---------------------------------------------------------------------------
__global__ __launch_bounds__(256) void gemm_b6(
    const float* __restrict__ A, long a_stride_t, long a_stride_b,
    const float* __restrict__ W,
    const float* __restrict__ bias,
    float* __restrict__ C,
    int M, int NN, int K)
{
    __shared__ __align__(16) short Ah[4][64][8], Am[4][64][8], Al[4][64][8];
    __shared__ __align__(16) short Bh[4][64][8], Bm[4][64][8], Bl[4][64][8];

    const int tid  = threadIdx.x;
    const int lane = tid & 63;
    const int wave = tid >> 6;
    const int bm   = blockIdx.x * 64;
    const int bn   = blockIdx.y * 64;
    const int mrow = (wave & 1) * 32;
    const int ncol = (wave >> 1) * 32;
    const int q    = lane >> 4;     // k-quad (0..3): k = q*8 + j
    const int l16  = lane & 15;

    // staging: thread -> (row 0..63, float4-chunk c0, c0+4) of the 64x32 tile
    const int arow = tid >> 2;
    const int c0   = tid & 3;
    const long aoff = (long)((bm + arow) >> 9) * a_stride_t
                    + (long)((bm + arow) & 511) * a_stride_b;
    const int  gnW  = bn + arow;
    const long woff = (long)gnW * (long)K;
    const bool wvalid = (gnW < NN);

    f32x4 accP[4] = {};   // chain P: hh, mh, lh
    f32x4 accQ[4] = {};   // chain Q: hm, mm, hl

    for (int k0 = 0; k0 < K; k0 += 32) {
        const bool full = (k0 + 32 <= K);
        #pragma unroll
        for (int cc = 0; cc < 2; cc++) {
            int c  = c0 + 4 * cc;       // chunk 0..7
            int kk = k0 + 4 * c;
            float fa[4], fw[4];
            if (full) {
                float4 va = *(const float4*)(A + aoff + kk);
                fa[0] = va.x; fa[1] = va.y; fa[2] = va.z; fa[3] = va.w;
                if (wvalid) {
                    float4 vw = *(const float4*)(W + woff + kk);
                    fw[0] = vw.x; fw[1] = vw.y; fw[2] = vw.z; fw[3] = vw.w;
                } else { fw[0] = fw[1] = fw[2] = fw[3] = 0.f; }
            } else {
                #pragma unroll
                for (int j = 0; j < 4; j++) {
                    int gk = kk + j;
                    fa[j] = (gk < K) ? A[aoff + gk] : 0.f;
                    fw[j] = (wvalid && gk < K) ? W[woff + gk] : 0.f;
                }
            }
            short4 ha, ma, la, hb, mb, lb;
            split3(fa[0], ha.x, ma.x, la.x); split3(fa[1], ha.y, ma.y, la.y);
            split3(fa[2], ha.z, ma.z, la.z); split3(fa[3], ha.w, ma.w, la.w);
            split3(fw[0], hb.x, mb.x, lb.x); split3(fw[1], hb.y, mb.y, lb.y);
            split3(fw[2], hb.z, mb.z, lb.z); split3(fw[3], hb.w, mb.w, lb.w);
            int kq = c >> 1, ko = (c & 1) * 4;
            *(short4*)&Ah[kq][arow][ko] = ha;
            *(short4*)&Am[kq][arow][ko] = ma;
            *(short4*)&Al[kq][arow][ko] = la;
            *(short4*)&Bh[kq][arow][ko] = hb;
            *(short4*)&Bm[kq][arow][ko] = mb;
            *(short4*)&Bl[kq][arow][ko] = lb;
        }
        __syncthreads();

        short8 a_h[2], a_m[2], a_l[2], b_h[2], b_m[2], b_l[2];
        #pragma unroll
        for (int ti = 0; ti < 2; ti++) {
            int r = mrow + ti * 16 + l16;
            a_h[ti] = *(const short8*)Ah[q][r];
            a_m[ti] = *(const short8*)Am[q][r];
            a_l[ti] = *(const short8*)Al[q][r];
            int n = ncol + ti * 16 + l16;
            b_h[ti] = *(const short8*)Bh[q][n];
            b_m[ti] = *(const short8*)Bm[q][n];
            b_l[ti] = *(const short8*)Bl[q][n];
        }
        #pragma unroll
        for (int ti = 0; ti < 2; ti++)
        #pragma unroll
        for (int tj = 0; tj < 2; tj++) {
            int t = ti * 2 + tj;
            accP[t] = __builtin_amdgcn_mfma_f32_16x16x32_bf16(a_h[ti], b_h[tj], accP[t], 0, 0, 0);
            accP[t] = __builtin_amdgcn_mfma_f32_16x16x32_bf16(a_m[ti], b_h[tj], accP[t], 0, 0, 0);
            accP[t] = __builtin_amdgcn_mfma_f32_16x16x32_bf16(a_l[ti], b_h[tj], accP[t], 0, 0, 0);
            accQ[t] = __builtin_amdgcn_mfma_f32_16x16x32_bf16(a_h[ti], b_m[tj], accQ[t], 0, 0, 0);
            accQ[t] = __builtin_amdgcn_mfma_f32_16x16x32_bf16(a_m[ti], b_m[tj], accQ[t], 0, 0, 0);
            accQ[t] = __builtin_amdgcn_mfma_f32_16x16x32_bf16(a_h[ti], b_l[tj], accQ[t], 0, 0, 0);
        }
        __syncthreads();
    }

    // epilogue: C/D layout col=lane&15, row=quad*4+reg
    #pragma unroll
    for (int ti = 0; ti < 2; ti++)
    #pragma unroll
    for (int tj = 0; tj < 2; tj++) {
        int t = ti * 2 + tj;
        f32x4 s = accP[t] + accQ[t];
        int gn = bn + ncol + tj * 16 + l16;
        if (gn < NN) {
            float bv = bias[gn];
            #pragma unroll
            for (int r = 0; r < 4; r++) {
                int gm = bm + mrow + ti * 16 + q * 4 + r;
                C[(long)gm * NN + gn] = s[r] + bv;
            }
        }
    }
}

// ---------------------------------------------------------------------------
// GRU elementwise update, float4-vectorized
// ---------------------------------------------------------------------------
__global__ __launch_bounds__(256) void gru_update4(
    const float4* __restrict__ gx,
    const float4* __restrict__ gh,
    const float4* __restrict__ hprev,
    float4* __restrict__ hnew)
{
    int idx = blockIdx.x * 256 + threadIdx.x;   // 0 .. B*H/4-1
    int b   = idx >> 8;                          // H/4 = 256 float4 per row
    int h4  = idx & 255;
    const float4* gxr = gx + (long)b * (G3 / 4);
    const float4* ghr = gh + (long)b * (G3 / 4);
    float4 xr = gxr[h4], xz = gxr[256 + h4], xn = gxr[512 + h4];
    float4 hr = ghr[h4], hz = ghr[256 + h4], hn = ghr[512 + h4];
    float4 hp = hprev[idx];
    float4 o;
#define GRUC(c) { \
    float r_ = 1.f / (1.f + expf(-(xr.c + hr.c))); \
    float z_ = 1.f / (1.f + expf(-(xz.c + hz.c))); \
    float n_ = tanhf(xn.c + r_ * hn.c); \
    o.c = (1.f - z_) * n_ + z_ * hp.c; }
    GRUC(x) GRUC(y) GRUC(z) GRUC(w)
#undef GRUC
    hnew[idx] = o;
}

// ---------------------------------------------------------------------------
// block reductions (256 threads = 4 waves of 64)
// ---------------------------------------------------------------------------
__device__ __forceinline__ float block_reduce_sum(float v) {
    __shared__ float red[4];
    #pragma unroll
    for (int o = 32; o > 0; o >>= 1) v += __shfl_down(v, o);
    __syncthreads();
    if ((threadIdx.x & 63) == 0) red[threadIdx.x >> 6] = v;
    __syncthreads();
    return red[0] + red[1] + red[2] + red[3];
}

__device__ __forceinline__ float block_reduce_max(float v) {
    __shared__ float red[4];
    #pragma unroll
    for (int o = 32; o > 0; o >>= 1) v = fmaxf(v, __shfl_down(v, o));
    __syncthreads();
    if ((threadIdx.x & 63) == 0) red[threadIdx.x >> 6] = v;
    __syncthreads();
    return fmaxf(fmaxf(red[0], red[1]), fmaxf(red[2], red[3]));
}

// ---------------------------------------------------------------------------
// LayerNorm + SiLU, in-place on z [B, H]; one block (256 thr) per row
// ---------------------------------------------------------------------------
__global__ __launch_bounds__(256) void ln_silu(
    float* __restrict__ z,
    const float* __restrict__ gamma,
    const float* __restrict__ beta)
{
    int b = blockIdx.x;
    float* row = z + (long)b * HID;
    float v[4];
    float s = 0.f;
    #pragma unroll
    for (int i = 0; i < 4; i++) { v[i] = row[threadIdx.x + 256 * i]; s += v[i]; }
    float mean = block_reduce_sum(s) * (1.f / HID);
    float vs = 0.f;
    #pragma unroll
    for (int i = 0; i < 4; i++) { float d = v[i] - mean; vs += d * d; }
    float var = block_reduce_sum(vs) * (1.f / HID);
    float inv = 1.f / sqrtf(var + 1e-5f);
    #pragma unroll
    for (int i = 0; i < 4; i++) {
        int col = threadIdx.x + 256 * i;
        float zz = (v[i] - mean) * inv * gamma[col] + beta[col];
        row[col] = zz / (1.f + expf(-zz));   // SiLU
    }
}

// ---------------------------------------------------------------------------
// mask(<0 -> -inf) + softmax + clip[0,0.1] + 20-iter rebalance; block per row
// ---------------------------------------------------------------------------
__global__ __launch_bounds__(256) void head_softmax_rebalance(
    const float* __restrict__ scores,
    float* __restrict__ out)
{
    int b = blockIdx.x;
    const float* srow = scores + (long)b * NIN;
    int i0 = threadIdx.x;
    int i1 = threadIdx.x + 256;
    bool v1 = (i1 < NIN);

    float s0 = srow[i0];
    if (s0 < 0.f) s0 = -INFINITY;
    float s1 = v1 ? srow[i1] : -INFINITY;
    if (s1 < 0.f) s1 = -INFINITY;

    float m  = block_reduce_max(fmaxf(s0, s1));
    float e0 = expf(s0 - m);
    float e1 = v1 ? expf(s1 - m) : 0.f;
    float Z  = block_reduce_sum(e0 + e1);

    float w0 = fminf(fmaxf(e0 / Z, 0.f), 0.1f);
    float w1 = v1 ? fminf(fmaxf(e1 / Z, 0.f), 0.1f) : 0.f;

    for (int it = 0; it < 20; it++) {
        float total  = block_reduce_sum(w0 + w1);
        float excess = total - 1.f;
        bool active  = excess > 1e-6f;
        float sur0 = fmaxf(w0 - 0.1f, 0.f);
        float sur1 = fmaxf(w1 - 0.1f, 0.f);
        float totsur = block_reduce_sum(sur0 + sur1);
        float u0, u1;
        if (totsur > 0.f) {
            float k = excess / fmaxf(totsur, 1e-12f);
            u0 = w0 - sur0 * k;
            u1 = w1 - sur1 * k;
        } else {
            u0 = w0 - excess / (float)NIN;
            u1 = w1 - excess / (float)NIN;
        }
        u0 = fminf(fmaxf(u0, 0.f), 0.1f);
        u1 = fminf(fmaxf(u1, 0.f), 0.1f);
        if (active) { w0 = u0; w1 = u1; }
    }

    out[(long)b * NIN + i0] = w0;
    if (v1) out[(long)b * NIN + i1] = w1;
}

// ---------------------------------------------------------------------------
extern "C" void kernel_launch(void* const* d_in, const int* in_sizes, int n_in,
                              void* d_out, int out_size, void* d_ws, size_t ws_size,
                              hipStream_t stream)
{
    const float* x     = (const float*)d_in[0];
    const float* w_ih0 = (const float*)d_in[1];
    const float* w_hh0 = (const float*)d_in[2];
    const float* b_ih0 = (const float*)d_in[3];
    const float* b_hh0 = (const float*)d_in[4];
    const float* w_ih1 = (const float*)d_in[5];
    const float* w_hh1 = (const float*)d_in[6];
    const float* b_ih1 = (const float*)d_in[7];
    const float* b_hh1 = (const float*)d_in[8];
    const float* w1    = (const float*)d_in[9];
    const float* b1    = (const float*)d_in[10];
    const float* ln_g  = (const float*)d_in[11];
    const float* ln_b  = (const float*)d_in[12];
    const float* w2    = (const float*)d_in[13];
    const float* b2    = (const float*)d_in[14];
    float* out = (float*)d_out;

    // ---- workspace layout ----
    float* ws = (float*)d_ws;
    float* h1a   = ws; ws += (size_t)BATCH * HID;
    float* h1b   = ws; ws += (size_t)BATCH * HID;
    float* hzero = ws; ws += (size_t)BATCH * HID;
    float* gh    = ws; ws += (size_t)BATCH * G3;
    float* zb    = ws; ws += (size_t)BATCH * HID;
    float* sc    = ws; ws += (size_t)BATCH * NIN;
    size_t fixed_floats = (size_t)(ws - (float*)d_ws);

    // choose chunk length Tc by available workspace
    int Tc = 1;
    const int cands[6] = {32, 16, 8, 4, 2, 1};
    for (int ci = 0; ci < 6; ci++) {
        size_t need = fixed_floats + (size_t)cands[ci] * BATCH * (G3 + HID);
        if (need * sizeof(float) <= ws_size) { Tc = cands[ci]; break; }
    }
    float* gxc   = ws; ws += (size_t)Tc * BATCH * G3;  // shared: gx0 then gx1
    float* h0seq = ws;                                  // [Tc][B][H]

    hipMemsetAsync(hzero, 0, (size_t)BATCH * HID * sizeof(float), stream);

    dim3 blk(256);
    dim3 gHH(BATCH / 64, G3 / 64);        // 8 x 48 recurrent gate GEMM
    dim3 gUpd((BATCH * HID / 4) / 256);   // 512

    const long sBH = (long)BATCH * HID;
    const long sBG = (long)BATCH * G3;

    for (int c = 0; c < SEQ_T / Tc; c++) {
        int t0 = c * Tc;
        // ---- layer-0 x-projection for the whole chunk (one big GEMM) ----
        dim3 gBig((Tc * BATCH) / 64, G3 / 64);
        gemm_b6<<<gBig, blk, 0, stream>>>(x + (long)t0 * NIN, (long)NIN, (long)SEQ_T * NIN,
                                          w_ih0, b_ih0, gxc, Tc * BATCH, G3, NIN);
        // ---- layer-0 recurrence over the chunk ----
        for (int tt = 0; tt < Tc; tt++) {
            const float* prev0 = (tt > 0) ? (h0seq + (long)(tt - 1) * sBH)
                               : (c > 0)  ? (h0seq + (long)(Tc - 1) * sBH)
                                          : hzero;
            gemm_b6<<<gHH, blk, 0, stream>>>(prev0, 0L, (long)HID, w_hh0, b_hh0, gh, BATCH, G3, HID);
            gru_update4<<<gUpd, blk, 0, stream>>>((const float4*)(gxc + (long)tt * sBG), (const float4*)gh,
                                                  (const float4*)prev0, (float4*)(h0seq + (long)tt * sBH));
        }
        // ---- layer-1 x-projection for the chunk (overwrites gxc) ----
        gemm_b6<<<gBig, blk, 0, stream>>>(h0seq, sBH, (long)HID,
                                          w_ih1, b_ih1, gxc, Tc * BATCH, G3, HID);
        // ---- layer-1 recurrence over the chunk ----
        for (int tt = 0; tt < Tc; tt++) {
            int t = t0 + tt;
            float* next1 = (t % 2 == 0) ? h1a : h1b;
            const float* prev1 = (t == 0) ? hzero : ((t % 2 == 0) ? h1b : h1a);
            gemm_b6<<<gHH, blk, 0, stream>>>(prev1, 0L, (long)HID, w_hh1, b_hh1, gh, BATCH, G3, HID);
            gru_update4<<<gUpd, blk, 0, stream>>>((const float4*)(gxc + (long)tt * sBG), (const float4*)gh,
                                                  (const float4*)prev1, (float4*)next1);
        }
    }
    const float* hT = (SEQ_T % 2 == 0) ? h1b : h1a;   // last write was t=127 (odd) -> h1b

    // ---- head ----
    dim3 gZ(BATCH / 64, HID / 64);
    gemm_b6<<<gZ, blk, 0, stream>>>(hT, 0L, (long)HID, w1, b1, zb, BATCH, HID, HID);
    ln_silu<<<dim3(BATCH), blk, 0, stream>>>(zb, ln_g, ln_b);
    dim3 gS(BATCH / 64, (NIN + 63) / 64);
    gemm_b6<<<gS, blk, 0, stream>>>(zb, 0L, (long)HID, w2, b2, sc, BATCH, NIN, HID);
    head_softmax_rebalance<<<dim3(BATCH), blk, 0, stream>>>(sc, out);
}